// Round 5
// baseline (4433.809 us; speedup 1.0000x reference)
//
#include <hip/hip_runtime.h>

static constexpr int Bsz = 512;
static constexpr int Tsz = 256;
static constexpr int Nsz = 128;
static constexpr int Msz = 256;

using short8 = __attribute__((ext_vector_type(8))) short;
using f32x4  = __attribute__((ext_vector_type(4))) float;

__device__ __forceinline__ float rcp_fast(float v){ return __builtin_amdgcn_rcpf(v); }
__device__ __forceinline__ float sigmoid_fast(float v){ return rcp_fast(1.0f + __expf(-v)); }
__device__ __forceinline__ float tanh_fast(float v){ return 1.0f - 2.0f * rcp_fast(1.0f + __expf(2.0f * v)); }
__device__ __forceinline__ unsigned short bf16r(float f){
  unsigned u = __float_as_uint(f);
  u += 0x7FFFu + ((u >> 16) & 1u);
  return (unsigned short)(u >> 16);
}

// ---------------------------------------------------------------------------
// K0: HS slab t=0 (bf16 h,s), zero scan flags, build We^T bf16 [u=256][k=512].
// HS layout: [t][b][j], j<256 -> h, j>=256 -> s (bf16, row stride 512)
// ---------------------------------------------------------------------------
__global__ __launch_bounds__(256) void k_init(const float* __restrict__ h_in,
                                              const float* __restrict__ s_in,
                                              const float* __restrict__ We,
                                              unsigned short* __restrict__ HS,
                                              unsigned short* __restrict__ Webt,
                                              int* __restrict__ flags){
  const int i = blockIdx.x * 256 + threadIdx.x;   // 0 .. 131071
  if (i < 255*8*16) flags[i] = 0;
  const float h = h_in[i];
  const float s = s_in[i];
  const int b = i >> 8;
  const int m = i & 255;
  unsigned short* row = HS + (size_t)b * 512;
  row[m]       = bf16r(h);
  row[256 + m] = bf16r(s);
  // We [512][256] fp32  ->  Webt [256][512] bf16
  const int k = i >> 8;     // 0..511
  const int u = i & 255;
  Webt[(size_t)u * 512 + k] = bf16r(We[(size_t)k * 256 + u]);
}

// ---------------------------------------------------------------------------
// K1: Q[b][n][u] = exp( 2 * sum_t x[b][t][n] * Ue[t][u] )   (r2, pre-exp'd)
// ---------------------------------------------------------------------------
__global__ __launch_bounds__(256) void k_r2exp(const float* __restrict__ x,
                                               const float* __restrict__ Ue,
                                               float* __restrict__ Q){
  const int b  = blockIdx.x;
  const int n0 = (blockIdx.y >> 2) * 64;
  const int u0 = (blockIdx.y & 3) * 64;
  __shared__ float Al[16][68];
  __shared__ float Bl[16][68];
  const int tid  = threadIdx.x;
  const int lane = tid & 63;
  const int kq   = tid >> 6;
  const int ty   = tid >> 4;
  const int tx   = tid & 15;
  float acc[4][4] = {};
  const float* xb = x + (size_t)b * Tsz * Nsz;
  for (int k0 = 0; k0 < Tsz; k0 += 16){
    #pragma unroll
    for (int i = 0; i < 4; ++i){
      const int k = kq*4 + i;
      Al[k][lane] = xb[(size_t)(k0+k)*Nsz + n0 + lane];
      Bl[k][lane] = Ue[(size_t)(k0+k)*Tsz + u0 + lane];
    }
    __syncthreads();
    #pragma unroll
    for (int kk = 0; kk < 16; ++kk){
      const float4 a = *(const float4*)&Al[kk][ty*4];
      const float4 w = *(const float4*)&Bl[kk][tx*4];
      const float av[4] = {a.x,a.y,a.z,a.w};
      const float wv[4] = {w.x,w.y,w.z,w.w};
      #pragma unroll
      for (int i=0;i<4;++i)
        #pragma unroll
        for (int j=0;j<4;++j)
          acc[i][j] = fmaf(av[i], wv[j], acc[i][j]);
    }
    __syncthreads();
  }
  float* Qb = Q + (size_t)b * Nsz * Tsz;
  #pragma unroll
  for (int i=0;i<4;++i){
    float4 v;
    v.x = __expf(2.0f*acc[i][0]);
    v.y = __expf(2.0f*acc[i][1]);
    v.z = __expf(2.0f*acc[i][2]);
    v.w = __expf(2.0f*acc[i][3]);
    *(float4*)&Qb[(size_t)(n0 + ty*4 + i)*Tsz + u0 + tx*4] = v;
  }
}

// ---------------------------------------------------------------------------
// K2: persistent LSTM scan, latency-pipelined.
// 128 blocks = 8 bg(64 b) x 16 ug(16 units). W bf16 frags in registers.
// Per step: poll peer flags -> issue h_t loads + x_{t+1} prefetch ->
// x-part MFMA (chunks 0..3, overlaps h latency) -> stage h -> h-part MFMA ->
// gates -> store h,s bf16 -> sync -> per-block flag release.
// ---------------------------------------------------------------------------
__global__ __launch_bounds__(256, 1) void k_scan(const float* __restrict__ x,
                                                 const float* __restrict__ Wk,
                                                 const float* __restrict__ Wr,
                                                 const float* __restrict__ bias,
                                                 const float* __restrict__ s_in,
                                                 unsigned short* __restrict__ HS,
                                                 int* __restrict__ flags){
  const int bg = blockIdx.x >> 4;     // batch group 0..7
  const int ug = blockIdx.x & 15;     // unit group 0..15
  const int b0 = bg * 64;
  const int u0 = ug * 16;
  const int tid  = threadIdx.x;
  const int w    = tid >> 6;          // wave 0..3 -> rows w*16..w*16+15
  const int lane = tid & 63;
  const int nl   = lane & 15;         // tile col / A row-within-tile
  const int kq   = lane >> 4;         // k quad

  __shared__ unsigned short Al[12*64*32];   // [chunk][row][32k] bf16, 48 KB

  // ---- preload W fragments (bf16) into registers: 12 chunks x 4 gates ----
  short8 wf[12][4];
  #pragma unroll
  for (int c = 0; c < 12; ++c){
    #pragma unroll
    for (int g = 0; g < 4; ++g){
      const int jcol = g*Msz + u0 + nl;
      short8 f;
      #pragma unroll
      for (int j = 0; j < 8; ++j){
        const int k = c*32 + kq*8 + j;
        const float wv = (k < Nsz) ? Wk[(size_t)k*(4*Msz) + jcol]
                                   : Wr[(size_t)(k - Nsz)*(4*Msz) + jcol];
        f[j] = (short)bf16r(wv);
      }
      wf[c][g] = f;
    }
  }

  // ---- per-lane state: 4 batch rows x 1 unit ----
  const int r0 = w*16 + kq*4;
  float bi[4];
  #pragma unroll
  for (int g = 0; g < 4; ++g) bi[g] = bias[g*Msz + u0 + nl];
  float s_reg[4];
  #pragma unroll
  for (int r = 0; r < 4; ++r)
    s_reg[r] = s_in[(size_t)(b0 + r0 + r)*Msz + u0 + nl];

  // ---- pre-stage x_0 into A chunks 0..3 ----
  {
    #pragma unroll
    for (int q = 0; q < 8; ++q){
      const int seg = tid*8 + q;
      const int row = seg >> 5;
      const int n   = (seg & 31) * 4;
      const float4 v = *(const float4*)(x + ((size_t)(b0+row)*Tsz + 0)*Nsz + n);
      ushort4 o;
      o.x = bf16r(v.x); o.y = bf16r(v.y); o.z = bf16r(v.z); o.w = bf16r(v.w);
      *(ushort4*)&Al[(n >> 5)*2048 + row*32 + (n & 31)] = o;
    }
  }
  __syncthreads();

  #pragma unroll 1
  for (int t = 0; t < Tsz - 1; ++t){
    // (a) wait for h_t (produced by peers at end of step t-1)
    if (t > 0){
      const int* fl = flags + ((size_t)(t-1)*8 + bg)*16;
      for (;;){
        const int v = __hip_atomic_load(fl + nl, __ATOMIC_ACQUIRE, __HIP_MEMORY_SCOPE_AGENT);
        if (__all(v != 0)) break;
        __builtin_amdgcn_s_sleep(4);
      }
    }
    // (b) issue h_t loads -> regs
    uint4 hreg[8];
    #pragma unroll
    for (int q = 0; q < 8; ++q){
      const int seg = tid*8 + q;
      const int row = seg >> 5;
      const int m   = (seg & 31) * 8;
      hreg[q] = *(const uint4*)(HS + ((size_t)t*Bsz + b0 + row)*512 + m);
    }
    // (b2) issue x_{t+1} prefetch -> regs
    float4 xpf[8];
    if (t < Tsz - 2){
      #pragma unroll
      for (int q = 0; q < 8; ++q){
        const int seg = tid*8 + q;
        const int row = seg >> 5;
        const int n   = (seg & 31) * 4;
        xpf[q] = *(const float4*)(x + ((size_t)(b0+row)*Tsz + (t+1))*Nsz + n);
      }
    }
    // (c) x-part MFMA (chunks 0..3) while h loads are in flight
    f32x4 acc0 = {0.f,0.f,0.f,0.f}, acc1 = {0.f,0.f,0.f,0.f};
    f32x4 acc2 = {0.f,0.f,0.f,0.f}, acc3 = {0.f,0.f,0.f,0.f};
    #pragma unroll
    for (int c = 0; c < 4; ++c){
      const short8 af = *(const short8*)&Al[c*2048 + (w*16 + nl)*32 + kq*8];
      acc0 = __builtin_amdgcn_mfma_f32_16x16x32_bf16(af, wf[c][0], acc0, 0, 0, 0);
      acc1 = __builtin_amdgcn_mfma_f32_16x16x32_bf16(af, wf[c][1], acc1, 0, 0, 0);
      acc2 = __builtin_amdgcn_mfma_f32_16x16x32_bf16(af, wf[c][2], acc2, 0, 0, 0);
      acc3 = __builtin_amdgcn_mfma_f32_16x16x32_bf16(af, wf[c][3], acc3, 0, 0, 0);
    }
    // (d) stage h_t -> A chunks 4..11
    #pragma unroll
    for (int q = 0; q < 8; ++q){
      const int seg = tid*8 + q;
      const int row = seg >> 5;
      const int m   = (seg & 31) * 8;
      const int k   = 128 + m;
      *(uint4*)&Al[(k >> 5)*2048 + row*32 + (k & 31)] = hreg[q];
    }
    // (e) h staged for all; also: all waves done reading chunks 0..3
    __syncthreads();
    // (f) overwrite chunks 0..3 with x_{t+1} (consumed next step, after (j))
    if (t < Tsz - 2){
      #pragma unroll
      for (int q = 0; q < 8; ++q){
        const int seg = tid*8 + q;
        const int row = seg >> 5;
        const int n   = (seg & 31) * 4;
        ushort4 o;
        o.x = bf16r(xpf[q].x); o.y = bf16r(xpf[q].y);
        o.z = bf16r(xpf[q].z); o.w = bf16r(xpf[q].w);
        *(ushort4*)&Al[(n >> 5)*2048 + row*32 + (n & 31)] = o;
      }
    }
    // (g) h-part MFMA (chunks 4..11)
    #pragma unroll
    for (int c = 4; c < 12; ++c){
      const short8 af = *(const short8*)&Al[c*2048 + (w*16 + nl)*32 + kq*8];
      acc0 = __builtin_amdgcn_mfma_f32_16x16x32_bf16(af, wf[c][0], acc0, 0, 0, 0);
      acc1 = __builtin_amdgcn_mfma_f32_16x16x32_bf16(af, wf[c][1], acc1, 0, 0, 0);
      acc2 = __builtin_amdgcn_mfma_f32_16x16x32_bf16(af, wf[c][2], acc2, 0, 0, 0);
      acc3 = __builtin_amdgcn_mfma_f32_16x16x32_bf16(af, wf[c][3], acc3, 0, 0, 0);
    }
    // (h) gate update + (i) store h,s bf16 to HS[t+1]
    #pragma unroll
    for (int r = 0; r < 4; ++r){
      const float ig = sigmoid_fast(acc0[r] + bi[0]);
      const float fg = sigmoid_fast(acc1[r] + bi[1]);
      const float gg = tanh_fast  (acc2[r] + bi[2]);
      const float og = sigmoid_fast(acc3[r] + bi[3]);
      const float s1 = fmaf(fg, s_reg[r], ig * gg);
      s_reg[r] = s1;
      const float hn = og * tanh_fast(s1);
      unsigned short* rp = HS + ((size_t)(t+1)*Bsz + b0 + r0 + r)*512;
      rp[u0 + nl]        = bf16r(hn);
      rp[256 + u0 + nl]  = bf16r(s1);
    }
    // (j) barrier drain (vmcnt(0) implied) — all stores + (f) writes done
    __syncthreads();
    // (k) publish
    if (tid == 0)
      __hip_atomic_store(flags + ((size_t)t*8 + bg)*16 + ug, 1,
                         __ATOMIC_RELEASE, __HIP_MEMORY_SCOPE_AGENT);
  }
}

// ---------------------------------------------------------------------------
// K3: attention. Per block (b, 16 t's):
//  r1 via bf16 MFMA (A from HS via LDS bounce, B = Webt), Pl = exp(2*r1);
//  e = -2*sum_u ve_u/(1+P*Q) (paired rcp); softmax over n; out = alpha*x.
// ---------------------------------------------------------------------------
__global__ __launch_bounds__(256) void k_attn(const unsigned short* __restrict__ HS,
                                              const float* __restrict__ Q,
                                              const unsigned short* __restrict__ Webt,
                                              const float* __restrict__ ve,
                                              const float* __restrict__ x,
                                              float* __restrict__ out){
  const int b  = blockIdx.x;
  const int t0 = blockIdx.y * 16;
  __shared__ unsigned short HSb[16*520];  // 16 rows x 512 (+8 pad)
  __shared__ float Pl[16][260];
  __shared__ float Ql[16][260];
  __shared__ float vel[256];
  __shared__ float El[16][128];
  __shared__ float red[16][16];
  __shared__ float rowm[16];
  __shared__ float rowsum[16];
  const int tid  = threadIdx.x;
  const int w    = tid >> 6;
  const int lane = tid & 63;
  const int nl   = lane & 15;
  const int kq   = lane >> 4;
  vel[tid] = ve[tid];
  // stage 16 HS rows (bf16) coalesced: 16 segs x 32 shorts = 512 per row
  {
    const int row = tid >> 4;
    const int seg = tid & 15;
    const unsigned short* src = HS + ((size_t)(t0 + row) * Bsz + b) * 512 + seg*32;
    #pragma unroll
    for (int i = 0; i < 4; ++i)   // 4 x uint4 = 32 shorts (was the R4 bug: i<2)
      *(uint4*)&HSb[row*520 + seg*32 + i*8] = *(const uint4*)(src + i*8);
  }
  __syncthreads();
  // r1 MFMA: rows = 16 t's, cols = 256 u, K = 512
  {
    short8 af[16];
    #pragma unroll
    for (int c = 0; c < 16; ++c)
      af[c] = *(const short8*)&HSb[nl*520 + c*32 + kq*8];
    #pragma unroll
    for (int ct = 0; ct < 4; ++ct){
      const int u0 = (w*4 + ct) * 16;
      f32x4 acc = {0.f,0.f,0.f,0.f};
      #pragma unroll
      for (int c = 0; c < 16; ++c){
        const short8 bf = *(const short8*)(Webt + (size_t)(u0 + nl)*512 + c*32 + kq*8);
        acc = __builtin_amdgcn_mfma_f32_16x16x32_bf16(af[c], bf, acc, 0, 0, 0);
      }
      #pragma unroll
      for (int r = 0; r < 4; ++r)
        Pl[kq*4 + r][u0 + nl] = __expf(2.0f * acc[r]);
    }
  }
  const int t  = tid >> 4;
  const int jn = tid & 15;
  for (int n0 = 0; n0 < Nsz; n0 += 16){
    __syncthreads();
    {
      const int row = tid >> 4;
      const int uc  = (tid & 15) * 16;
      const float* src = Q + ((size_t)b * Nsz + n0 + row) * Tsz + uc;
      #pragma unroll
      for (int i = 0; i < 4; ++i)
        *(float4*)&Ql[row][uc + i*4] = *(const float4*)&src[i*4];
    }
    __syncthreads();
    float acc = 0.0f;
    #pragma unroll 8
    for (int u = 0; u < Tsz; u += 4){
      const float4 p4 = *(const float4*)&Pl[t][u];
      const float4 q4 = *(const float4*)&Ql[jn][u];
      const float4 v4 = *(const float4*)&vel[u];
      const float za = fmaf(p4.x, q4.x, 1.0f);
      const float zb = fmaf(p4.y, q4.y, 1.0f);
      const float zc = fmaf(p4.z, q4.z, 1.0f);
      const float zd = fmaf(p4.w, q4.w, 1.0f);
      const float n1 = fmaf(v4.x, zb, v4.y * za);
      const float n2 = fmaf(v4.z, zd, v4.w * zc);
      acc = fmaf(n1, rcp_fast(za * zb), acc);
      acc = fmaf(n2, rcp_fast(zc * zd), acc);
    }
    El[t][n0 + jn] = -2.0f * acc;
  }
  __syncthreads();
  // softmax over n (128) per t row; 16 threads per row, 8 n each
  const int j = jn;
  float mx = -3.0e38f;
  #pragma unroll
  for (int q=0;q<8;++q) mx = fmaxf(mx, El[t][j*8+q]);
  red[t][j] = mx;
  __syncthreads();
  if (j == 0){
    float m2 = red[t][0];
    #pragma unroll
    for (int q=1;q<16;++q) m2 = fmaxf(m2, red[t][q]);
    rowm[t] = m2;
  }
  __syncthreads();
  const float rm = rowm[t];
  float sm = 0.0f;
  #pragma unroll
  for (int q=0;q<8;++q){
    const float p = __expf(El[t][j*8+q] - rm);
    El[t][j*8+q] = p;
    sm += p;
  }
  red[t][j] = sm;
  __syncthreads();
  if (j == 0){
    float s2 = 0.0f;
    #pragma unroll
    for (int q=0;q<16;++q) s2 += red[t][q];
    rowsum[t] = s2;
  }
  __syncthreads();
  const float inv = rcp_fast(rowsum[t]);
  const float* xr   = x   + ((size_t)b*Tsz + t0 + t)*Nsz + j*8;
  float*       orow = out + ((size_t)b*Tsz + t0 + t)*Nsz + j*8;
  #pragma unroll
  for (int q=0;q<8;++q)
    orow[q] = El[t][j*8+q] * inv * xr[q];
}

// ---------------------------------------------------------------------------
extern "C" void kernel_launch(void* const* d_in, const int* in_sizes, int n_in,
                              void* d_out, int out_size, void* d_ws, size_t ws_size,
                              hipStream_t stream){
  const float* x    = (const float*)d_in[0];
  const float* s_in = (const float*)d_in[1];
  const float* h_in = (const float*)d_in[2];
  const float* We   = (const float*)d_in[3];
  const float* Ue   = (const float*)d_in[4];
  const float* ve   = (const float*)d_in[5];
  const float* Wk   = (const float*)d_in[6];
  const float* Wr   = (const float*)d_in[7];
  const float* bias = (const float*)d_in[8];
  float* out = (float*)d_out;

  // ws: Q fp32 (67MB) | HS bf16 (134MB) | Webt bf16 (256KB) | flags (128KB)
  float* Q = (float*)d_ws;
  unsigned short* HS   = (unsigned short*)(Q + (size_t)Bsz*Nsz*Tsz);
  unsigned short* Webt = HS + (size_t)Tsz*Bsz*512;
  int* flags = (int*)(Webt + (size_t)256*512);

  k_init<<<(Bsz*Msz)/256, 256, 0, stream>>>(h_in, s_in, We, HS, Webt, flags);
  k_r2exp<<<dim3(Bsz, 8), 256, 0, stream>>>(x, Ue, Q);
  k_scan<<<128, 256, 0, stream>>>(x, Wk, Wr, bias, s_in, HS, flags);
  k_attn<<<dim3(Bsz, Tsz/16), 256, 0, stream>>>(HS, Q, Webt, ve, x, out);
}